// Round 4
// baseline (261.193 us; speedup 1.0000x reference)
//
#include <hip/hip_runtime.h>
#include <hip/hip_bf16.h>
#include <cstdint>

#define NROWS 1000000
#define NCLS  128
#define NBINS 15

// conf in (1/128, 1) strictly for this data; cover [2^-9, 1] to be safe.
#define FBASE 0x3B000000u
#define NB    73728          // (0x3F800000 - 0x3B000000) >> 10
#define SCAN_T 1024
#define PER   (NB / SCAN_T)  // 72

// workspace layout (bytes)
#define OFF_CONF   0u
#define OFF_ACC    4000000u
#define OFF_HIST   5000000u
#define OFF_SUB    5294912u   // 30 slots * 1024 u32
#define OFF_BINS   5417792u   // 45 doubles: cnt[15], csum[15], asum[15]
#define OFF_DONE   5418152u   // 2 u32 done-counters (+ pad)
#define OFF_TGTB   5418168u
#define OFF_TGTL   5418288u
#define OFF_EDGES  5418408u
#define ZERO_BYTES (OFF_TGTB - OFF_HIST)   // hist + sub + bins + done

#define ROW_BLOCKS 2048

// ---------------- kernel 1: per-row conf/acc + coarse histogram ----------------
// Persistent grid-stride; 16 lanes per row, 2 adjacent rows per thread per iter.
__device__ __forceinline__ void reduce_row(float4 v0, float4 v1, int l16,
                                           float& c_out, int& mi_out)
{
    const int b0 = l16 * 4, b1 = 64 + l16 * 4;
    float m = v0.x; int mi = b0;
    if (v0.y > m) { m = v0.y; mi = b0 + 1; }
    if (v0.z > m) { m = v0.z; mi = b0 + 2; }
    if (v0.w > m) { m = v0.w; mi = b0 + 3; }
    if (v1.x > m) { m = v1.x; mi = b1; }
    if (v1.y > m) { m = v1.y; mi = b1 + 1; }
    if (v1.z > m) { m = v1.z; mi = b1 + 2; }
    if (v1.w > m) { m = v1.w; mi = b1 + 3; }
#pragma unroll
    for (int d = 1; d < 16; d <<= 1) {          // stays within 16-lane group
        float om = __shfl_xor(m, d);
        int   oi = __shfl_xor(mi, d);
        if (om > m || (om == m && oi < mi)) { m = om; mi = oi; }
    }
    float s = __expf(v0.x - m) + __expf(v0.y - m) + __expf(v0.z - m) + __expf(v0.w - m)
            + __expf(v1.x - m) + __expf(v1.y - m) + __expf(v1.z - m) + __expf(v1.w - m);
#pragma unroll
    for (int d = 1; d < 16; d <<= 1) s += __shfl_xor(s, d);
    c_out  = 1.0f / s;
    mi_out = mi;
}

__device__ __forceinline__ int bucket_of(float c)
{
    int ub = (int)(__float_as_uint(c) - FBASE);
    int b  = ub >> 10;
    return b < 0 ? 0 : (b >= NB ? NB - 1 : b);
}

__global__ __launch_bounds__(256) void k_row(const float* __restrict__ logits,
                                             const int* __restrict__ labels,
                                             float* __restrict__ conf,
                                             unsigned char* __restrict__ acc,
                                             unsigned int* __restrict__ hist)
{
    const int g   = threadIdx.x >> 4;      // group 0..15 within block
    const int l16 = threadIdx.x & 15;
    const float4* lg4 = reinterpret_cast<const float4*>(logits);

    // block handles 32 rows per sweep; group g owns rows base+2g, base+2g+1
    for (long long base = (long long)blockIdx.x * 32; base < NROWS;
         base += (long long)ROW_BLOCKS * 32) {
        const long long rowA = base + g * 2;

        const float4* p = lg4 + rowA * (NCLS / 4) + l16;
        const float4 a0 = p[0],  a1 = p[16];   // row rowA
        const float4 b0 = p[32], b1 = p[48];   // row rowA+1
        const int2 lab = *reinterpret_cast<const int2*>(labels + rowA);

        float cA, cB; int miA, miB;
        reduce_row(a0, a1, l16, cA, miA);
        reduce_row(b0, b1, l16, cB, miB);

        if (l16 == 0) {
            *reinterpret_cast<float2*>(conf + rowA) = make_float2(cA, cB);
            uchar2 a;
            a.x = (lab.x == miA) ? 1 : 0;
            a.y = (lab.y == miB) ? 1 : 0;
            *reinterpret_cast<uchar2*>(acc + rowA) = a;
            atomicAdd(&hist[bucket_of(cA)], 1u);
            atomicAdd(&hist[bucket_of(cB)], 1u);
        }
    }
}

// ---------------- kernel 2: scan histogram, locate 30 target ranks ----------------
__device__ __forceinline__ unsigned int rank_of(int s)
{
    if (s == 0)  return 0u;
    if (s == 29) return (unsigned int)(NROWS - 1);
    int i = (s + 1) >> 1;                              // 1..14
    unsigned int k = (unsigned int)((long long)i * NROWS / 15);  // floor(i*N/15)
    return k + ((s & 1) ? 0u : 1u);                    // odd slot: k, even slot: k+1
}

__global__ __launch_bounds__(SCAN_T) void k_scan(const unsigned int* __restrict__ hist,
                                                 int* __restrict__ tgtb,
                                                 int* __restrict__ tgtl)
{
    __shared__ unsigned int v[SCAN_T];
    const int t = threadIdx.x;
    unsigned int s = 0;
    for (int j = 0; j < PER; j++) s += hist[t * PER + j];
    v[t] = s;
    __syncthreads();
    // Hillis-Steele inclusive scan over 1024 chunk sums
    for (int off = 1; off < SCAN_T; off <<= 1) {
        unsigned int x = (t >= off) ? v[t - off] : 0u;
        __syncthreads();
        v[t] += x;
        __syncthreads();
    }
    const unsigned int run0 = v[t] - s;   // exclusive prefix of this thread's chunk
    for (int s2 = 0; s2 < 30; s2++) {
        unsigned int r = rank_of(s2);
        if (r >= run0 && r < run0 + s) {  // rank falls in my chunk: walk it
            unsigned int run = run0;
            for (int j = 0; j < PER; j++) {
                unsigned int c = hist[t * PER + j];
                if (r < run + c) { tgtb[s2] = t * PER + j; tgtl[s2] = (int)(r - run); break; }
                run += c;
            }
        }
    }
}

// ------- kernel 3: sub-histogram (low 10 bits) for target buckets + fused edges -------
__global__ __launch_bounds__(256) void k_subhist(const float* __restrict__ conf,
                                                 const int* __restrict__ tgtb,
                                                 const int* __restrict__ tgtl,
                                                 unsigned int* __restrict__ sub,
                                                 float* __restrict__ edges,
                                                 unsigned int* __restrict__ done)
{
    __shared__ int tb[30];
    if (threadIdx.x < 30) tb[threadIdx.x] = tgtb[threadIdx.x];
    __syncthreads();
    const int stride = gridDim.x * blockDim.x;
    for (int i = blockIdx.x * blockDim.x + threadIdx.x; i < NROWS / 4; i += stride) {
        float4 c4 = reinterpret_cast<const float4*>(conf)[i];
        float cv[4] = {c4.x, c4.y, c4.z, c4.w};
#pragma unroll
        for (int e = 0; e < 4; e++) {
            int ub = (int)(__float_as_uint(cv[e]) - FBASE);
            int b  = ub >> 10;
            b = b < 0 ? 0 : (b >= NB ? NB - 1 : b);
            int lo = ub & 1023;
            for (int s = 0; s < 30; s++)
                if (b == tb[s]) atomicAdd(&sub[s * 1024 + lo], 1u);
        }
    }

    // last-block: resolve exact order-stat values and build edges
    __syncthreads();
    __shared__ unsigned int isLast;
    if (threadIdx.x == 0) {
        __threadfence();
        isLast = (atomicAdd(done, 1u) == gridDim.x - 1) ? 1u : 0u;
    }
    __syncthreads();
    if (!isLast) return;
    __threadfence();                       // acquire side

    __shared__ float val[32];
    const int k = threadIdx.x & 31;
    for (int slot = threadIdx.x >> 5; slot < 30; slot += 8) {
        const unsigned int local = (unsigned int)tgtl[slot];
        unsigned int cs[32];
        unsigned int csum = 0;
        const unsigned int* q = sub + slot * 1024 + k * 32;
#pragma unroll
        for (int j = 0; j < 32; j++) { cs[j] = q[j]; csum += cs[j]; }
        unsigned int incl = csum;
#pragma unroll
        for (int off = 1; off < 32; off <<= 1) {     // guarded: never crosses 32-group
            unsigned int x = __shfl_up(incl, off);
            if (k >= off) incl += x;
        }
        const unsigned int excl = incl - csum;
        if (local >= excl && local < excl + csum) {   // exactly one lane hits
            unsigned int run = excl;
            int subidx = 0;
#pragma unroll
            for (int j = 0; j < 32; j++) {
                if (local >= run && local < run + cs[j]) subidx = k * 32 + j;
                run += cs[j];
            }
            unsigned int bits = FBASE + ((unsigned int)tb[slot] << 10) + (unsigned int)subidx;
            val[slot] = __uint_as_float(bits);
        }
    }
    __syncthreads();
    if (threadIdx.x == 0) {
        edges[0]  = val[0];
        edges[15] = val[29];
        for (int i = 1; i <= 14; i++) {
            double q = (double)i * (double)NROWS / 15.0;
            long long kk = (long long)i * NROWS / 15;
            double f = q - (double)kk;
            edges[i] = (float)((1.0 - f) * (double)val[2 * i - 1] + f * (double)val[2 * i]);
        }
    }
}

// ---------------- kernel 4: bin sums + fused final ECE ----------------
__global__ __launch_bounds__(256) void k_bin(const float* __restrict__ conf,
                                             const unsigned char* __restrict__ acc,
                                             const float* __restrict__ edges,
                                             double* __restrict__ bins,
                                             unsigned int* __restrict__ done,
                                             float* __restrict__ out)
{
    __shared__ float se[16];
    __shared__ float lc[4][16], ls[4][16], la[4][16];   // per-wave bins
    const int w = threadIdx.x >> 6;
    if (threadIdx.x < 16) se[threadIdx.x] = edges[threadIdx.x];
    if (threadIdx.x < 64) {
        int a = threadIdx.x >> 4, b = threadIdx.x & 15;
        lc[a][b] = 0.f; ls[a][b] = 0.f; la[a][b] = 0.f;
    }
    __syncthreads();
    const int stride = gridDim.x * blockDim.x;
    for (int i = blockIdx.x * blockDim.x + threadIdx.x; i < NROWS / 4; i += stride) {
        float4 c4 = reinterpret_cast<const float4*>(conf)[i];
        uchar4 a4 = reinterpret_cast<const uchar4*>(acc)[i];
        float cv[4] = {c4.x, c4.y, c4.z, c4.w};
        unsigned char av[4] = {a4.x, a4.y, a4.z, a4.w};
#pragma unroll
        for (int e = 0; e < 4; e++) {
            float v = cv[e];
            if (v > se[0] && v <= se[15]) {       // valid; else dropped
                int idx = 0;
#pragma unroll
                for (int j = 1; j <= 14; j++) idx += (se[j] < v) ? 1 : 0;  // searchsorted left
                atomicAdd(&lc[w][idx], 1.0f);
                atomicAdd(&ls[w][idx], v);
                atomicAdd(&la[w][idx], (float)av[e]);
            }
        }
    }
    __syncthreads();
    if (threadIdx.x < 15) {
        int t = threadIdx.x;
        atomicAdd(&bins[t],      (double)(lc[0][t] + lc[1][t] + lc[2][t] + lc[3][t]));
        atomicAdd(&bins[15 + t], (double)(ls[0][t] + ls[1][t] + ls[2][t] + ls[3][t]));
        atomicAdd(&bins[30 + t], (double)(la[0][t] + la[1][t] + la[2][t] + la[3][t]));
    }

    // last-block: final ECE
    __syncthreads();
    __shared__ unsigned int isLast;
    if (threadIdx.x == 0) {
        __threadfence();
        isLast = (atomicAdd(done, 1u) == gridDim.x - 1) ? 1u : 0u;
    }
    __syncthreads();
    if (isLast && threadIdx.x == 0) {
        __threadfence();                   // acquire side
        double ece = 0.0;
        for (int b = 0; b < NBINS; b++) {
            double cnt = bins[b];
            if (cnt > 0.0) {
                double safe = cnt < 1.0 ? 1.0 : cnt;
                double gap  = fabs(bins[15 + b] / safe - bins[30 + b] / safe);
                ece += gap * (cnt / (double)NROWS);
            }
        }
        out[0] = (float)ece;
    }
}

extern "C" void kernel_launch(void* const* d_in, const int* in_sizes, int n_in,
                              void* d_out, int out_size, void* d_ws, size_t ws_size,
                              hipStream_t stream)
{
    const float* logits = (const float*)d_in[0];
    const int*   labels = (const int*)d_in[1];
    char* ws = (char*)d_ws;

    float*         conf  = (float*)(ws + OFF_CONF);
    unsigned char* acc   = (unsigned char*)(ws + OFF_ACC);
    unsigned int*  hist  = (unsigned int*)(ws + OFF_HIST);
    unsigned int*  sub   = (unsigned int*)(ws + OFF_SUB);
    double*        bins  = (double*)(ws + OFF_BINS);
    unsigned int*  done  = (unsigned int*)(ws + OFF_DONE);
    int*           tgtb  = (int*)(ws + OFF_TGTB);
    int*           tgtl  = (int*)(ws + OFF_TGTL);
    float*         edges = (float*)(ws + OFF_EDGES);

    hipMemsetAsync(ws + OFF_HIST, 0, ZERO_BYTES, stream);

    k_row<<<ROW_BLOCKS, 256, 0, stream>>>(logits, labels, conf, acc, hist);
    k_scan<<<1, SCAN_T, 0, stream>>>(hist, tgtb, tgtl);
    k_subhist<<<1024, 256, 0, stream>>>(conf, tgtb, tgtl, sub, edges, done);
    k_bin<<<1024, 256, 0, stream>>>(conf, acc, edges, bins, done + 1, (float*)d_out);
}

// Round 5
// 233.896 us; speedup vs baseline: 1.1167x; 1.1167x over previous
//
#include <hip/hip_runtime.h>
#include <hip/hip_bf16.h>
#include <cstdint>

#define NROWS 1000000
#define NCLS  128
#define NBINS 15

// conf in (1/128, 1) strictly for this data; cover [2^-9, 1] to be safe.
#define FBASE 0x3B000000u
#define NB    73728          // (0x3F800000 - 0x3B000000) >> 10
#define SCAN_T 1024
#define PER   (NB / SCAN_T)  // 72

// workspace layout (bytes)
#define OFF_CONF   0u
#define OFF_ACC    4000000u
#define OFF_HIST   5000000u
#define OFF_SUB    5294912u   // 30 slots * 1024 u32
#define OFF_BINS   5417792u   // 45 doubles: cnt[15], csum[15], asum[15]
#define OFF_TGTB   5418152u
#define OFF_TGTL   5418272u
#define OFF_EDGES  5418392u
#define ZERO_BYTES (OFF_TGTB - OFF_HIST)   // hist + subhist + bins

// ---------------- kernel 1: per-row conf/acc + coarse histogram ----------------
// 32 lanes per row: every wave-level load instr covers exactly 1 KB contiguous
// (rows r, r+1). Each thread reduces 2 rows (r and r+8) -> 2 loads in flight.
__device__ __forceinline__ void reduce32(float4 v, int l32, float& c_out, int& mi_out)
{
    const int b = l32 * 4;
    float m = v.x; int mi = b;
    if (v.y > m) { m = v.y; mi = b + 1; }
    if (v.z > m) { m = v.z; mi = b + 2; }
    if (v.w > m) { m = v.w; mi = b + 3; }
#pragma unroll
    for (int d = 1; d < 32; d <<= 1) {          // stays within 32-lane half
        float om = __shfl_xor(m, d);
        int   oi = __shfl_xor(mi, d);
        if (om > m || (om == m && oi < mi)) { m = om; mi = oi; }
    }
    float s = __expf(v.x - m) + __expf(v.y - m) + __expf(v.z - m) + __expf(v.w - m);
#pragma unroll
    for (int d = 1; d < 32; d <<= 1) s += __shfl_xor(s, d);
    c_out  = 1.0f / s;
    mi_out = mi;
}

__device__ __forceinline__ int bucket_of(float c)
{
    int ub = (int)(__float_as_uint(c) - FBASE);
    int b  = ub >> 10;
    return b < 0 ? 0 : (b >= NB ? NB - 1 : b);
}

__global__ __launch_bounds__(256) void k_row(const float* __restrict__ logits,
                                             const int* __restrict__ labels,
                                             float* __restrict__ conf,
                                             unsigned char* __restrict__ acc,
                                             unsigned int* __restrict__ hist)
{
    const int h   = threadIdx.x >> 5;      // half-wave 0..7
    const int l32 = threadIdx.x & 31;
    const long long rA = (long long)blockIdx.x * 16 + h;   // block covers 16 rows
    const long long rB = rA + 8;

    const float4* p = reinterpret_cast<const float4*>(logits);
    const float4 va = p[rA * 32 + l32];    // wave instr: rows rA(base+2w),rA+1 -> 1KB contiguous
    const float4 vb = p[rB * 32 + l32];    // wave instr: rows rB,rB+1 -> 1KB contiguous
    const int labA = labels[rA];
    const int labB = labels[rB];

    float cA, cB; int miA, miB;
    reduce32(va, l32, cA, miA);
    reduce32(vb, l32, cB, miB);

    if (l32 == 0) {
        conf[rA] = cA;
        acc[rA]  = (labA == miA) ? 1u : 0u;
        atomicAdd(&hist[bucket_of(cA)], 1u);
        conf[rB] = cB;
        acc[rB]  = (labB == miB) ? 1u : 0u;
        atomicAdd(&hist[bucket_of(cB)], 1u);
    }
}

// ---------------- kernel 2: scan histogram, locate 30 target ranks ----------------
__device__ __forceinline__ unsigned int rank_of(int s)
{
    if (s == 0)  return 0u;
    if (s == 29) return (unsigned int)(NROWS - 1);
    int i = (s + 1) >> 1;                              // 1..14
    unsigned int k = (unsigned int)((long long)i * NROWS / 15);  // floor(i*N/15)
    return k + ((s & 1) ? 0u : 1u);                    // odd slot: k, even slot: k+1
}

__global__ __launch_bounds__(SCAN_T) void k_scan(const unsigned int* __restrict__ hist,
                                                 int* __restrict__ tgtb,
                                                 int* __restrict__ tgtl)
{
    __shared__ unsigned int v[SCAN_T];
    const int t = threadIdx.x;
    unsigned int s = 0;
    for (int j = 0; j < PER; j++) s += hist[t * PER + j];
    v[t] = s;
    __syncthreads();
    // Hillis-Steele inclusive scan over 1024 chunk sums
    for (int off = 1; off < SCAN_T; off <<= 1) {
        unsigned int x = (t >= off) ? v[t - off] : 0u;
        __syncthreads();
        v[t] += x;
        __syncthreads();
    }
    const unsigned int run0 = v[t] - s;   // exclusive prefix of this thread's chunk
    for (int s2 = 0; s2 < 30; s2++) {
        unsigned int r = rank_of(s2);
        if (r >= run0 && r < run0 + s) {  // rank falls in my chunk: walk it
            unsigned int run = run0;
            for (int j = 0; j < PER; j++) {
                unsigned int c = hist[t * PER + j];
                if (r < run + c) { tgtb[s2] = t * PER + j; tgtl[s2] = (int)(r - run); break; }
                run += c;
            }
        }
    }
}

// ---------------- kernel 3: sub-histogram (low 10 bits) for target buckets ----------------
__global__ __launch_bounds__(256) void k_subhist(const float* __restrict__ conf,
                                                 const int* __restrict__ tgtb,
                                                 unsigned int* __restrict__ sub)
{
    __shared__ int tb[30];
    if (threadIdx.x < 30) tb[threadIdx.x] = tgtb[threadIdx.x];
    __syncthreads();
    const int stride = gridDim.x * blockDim.x;
    for (int i = blockIdx.x * blockDim.x + threadIdx.x; i < NROWS / 4; i += stride) {
        float4 c4 = reinterpret_cast<const float4*>(conf)[i];
        float cv[4] = {c4.x, c4.y, c4.z, c4.w};
#pragma unroll
        for (int e = 0; e < 4; e++) {
            int ub = (int)(__float_as_uint(cv[e]) - FBASE);
            int b  = ub >> 10;
            b = b < 0 ? 0 : (b >= NB ? NB - 1 : b);
            int lo = ub & 1023;
            for (int s = 0; s < 30; s++)
                if (b == tb[s]) atomicAdd(&sub[s * 1024 + lo], 1u);
        }
    }
}

// ---------------- kernel 4: resolve exact order-stat values, build edges ----------------
__global__ __launch_bounds__(1024) void k_edges(const unsigned int* __restrict__ sub,
                        const int* __restrict__ tgtb,
                        const int* __restrict__ tgtl,
                        float* __restrict__ edges)
{
    __shared__ float val[32];
    const int g = threadIdx.x >> 5;    // slot 0..31 (30 used)
    const int k = threadIdx.x & 31;    // lane within slot group
    if (g < 30) {
        const unsigned int local = (unsigned int)tgtl[g];
        unsigned int cs[32];
        unsigned int csum = 0;
        const unsigned int* p = sub + g * 1024 + k * 32;
#pragma unroll
        for (int j = 0; j < 32; j++) { cs[j] = p[j]; csum += cs[j]; }
        // inclusive scan across the 32-lane group (guarded shfl_up)
        unsigned int incl = csum;
#pragma unroll
        for (int off = 1; off < 32; off <<= 1) {
            unsigned int x = __shfl_up(incl, off);
            if (k >= off) incl += x;
        }
        const unsigned int excl = incl - csum;
        if (local >= excl && local < excl + csum) {   // exactly one lane hits
            unsigned int run = excl;
            int subidx = 0;
#pragma unroll
            for (int j = 0; j < 32; j++) {
                if (local >= run && local < run + cs[j]) subidx = k * 32 + j;
                run += cs[j];
            }
            unsigned int bits = FBASE + ((unsigned int)tgtb[g] << 10) + (unsigned int)subidx;
            val[g] = __uint_as_float(bits);
        }
    }
    __syncthreads();
    if (threadIdx.x == 0) {
        edges[0]  = val[0];
        edges[15] = val[29];
        for (int i = 1; i <= 14; i++) {
            double q = (double)i * (double)NROWS / 15.0;
            long long kk = (long long)i * NROWS / 15;
            double f = q - (double)kk;
            edges[i] = (float)((1.0 - f) * (double)val[2 * i - 1] + f * (double)val[2 * i]);
        }
    }
}

// ---------------- kernel 5: bin counts / conf-sums / acc-sums ----------------
__global__ __launch_bounds__(256) void k_bin(const float* __restrict__ conf,
                                             const unsigned char* __restrict__ acc,
                                             const float* __restrict__ edges,
                                             double* __restrict__ bins)
{
    __shared__ float se[16];
    __shared__ float lc[4][16], ls[4][16], la[4][16];   // per-wave bins
    const int w = threadIdx.x >> 6;
    if (threadIdx.x < 16) se[threadIdx.x] = edges[threadIdx.x];
    if (threadIdx.x < 64) {
        int a = threadIdx.x >> 4, b = threadIdx.x & 15;
        lc[a][b] = 0.f; ls[a][b] = 0.f; la[a][b] = 0.f;
    }
    __syncthreads();
    const int stride = gridDim.x * blockDim.x;
    for (int i = blockIdx.x * blockDim.x + threadIdx.x; i < NROWS / 4; i += stride) {
        float4 c4 = reinterpret_cast<const float4*>(conf)[i];
        uchar4 a4 = reinterpret_cast<const uchar4*>(acc)[i];
        float cv[4] = {c4.x, c4.y, c4.z, c4.w};
        unsigned char av[4] = {a4.x, a4.y, a4.z, a4.w};
#pragma unroll
        for (int e = 0; e < 4; e++) {
            float v = cv[e];
            if (v > se[0] && v <= se[15]) {       // valid; else dropped
                int idx = 0;
#pragma unroll
                for (int j = 1; j <= 14; j++) idx += (se[j] < v) ? 1 : 0;  // searchsorted left
                atomicAdd(&lc[w][idx], 1.0f);
                atomicAdd(&ls[w][idx], v);
                atomicAdd(&la[w][idx], (float)av[e]);
            }
        }
    }
    __syncthreads();
    if (threadIdx.x < 15) {
        int t = threadIdx.x;
        atomicAdd(&bins[t],      (double)(lc[0][t] + lc[1][t] + lc[2][t] + lc[3][t]));
        atomicAdd(&bins[15 + t], (double)(ls[0][t] + ls[1][t] + ls[2][t] + ls[3][t]));
        atomicAdd(&bins[30 + t], (double)(la[0][t] + la[1][t] + la[2][t] + la[3][t]));
    }
}

// ---------------- kernel 6: final ECE ----------------
__global__ void k_final(const double* __restrict__ bins, float* __restrict__ out)
{
    if (threadIdx.x == 0 && blockIdx.x == 0) {
        double ece = 0.0;
        for (int b = 0; b < NBINS; b++) {
            double cnt = bins[b];
            if (cnt > 0.0) {
                double safe = cnt < 1.0 ? 1.0 : cnt;
                double gap  = fabs(bins[15 + b] / safe - bins[30 + b] / safe);
                ece += gap * (cnt / (double)NROWS);
            }
        }
        out[0] = (float)ece;
    }
}

extern "C" void kernel_launch(void* const* d_in, const int* in_sizes, int n_in,
                              void* d_out, int out_size, void* d_ws, size_t ws_size,
                              hipStream_t stream)
{
    const float* logits = (const float*)d_in[0];
    const int*   labels = (const int*)d_in[1];
    char* ws = (char*)d_ws;

    float*         conf  = (float*)(ws + OFF_CONF);
    unsigned char* acc   = (unsigned char*)(ws + OFF_ACC);
    unsigned int*  hist  = (unsigned int*)(ws + OFF_HIST);
    unsigned int*  sub   = (unsigned int*)(ws + OFF_SUB);
    double*        bins  = (double*)(ws + OFF_BINS);
    int*           tgtb  = (int*)(ws + OFF_TGTB);
    int*           tgtl  = (int*)(ws + OFF_TGTL);
    float*         edges = (float*)(ws + OFF_EDGES);

    hipMemsetAsync(ws + OFF_HIST, 0, ZERO_BYTES, stream);

    k_row<<<NROWS / 16, 256, 0, stream>>>(logits, labels, conf, acc, hist);
    k_scan<<<1, SCAN_T, 0, stream>>>(hist, tgtb, tgtl);
    k_subhist<<<1024, 256, 0, stream>>>(conf, tgtb, sub);
    k_edges<<<1, 1024, 0, stream>>>(sub, tgtb, tgtl, edges);
    k_bin<<<1024, 256, 0, stream>>>(conf, acc, edges, bins);
    k_final<<<1, 64, 0, stream>>>(bins, (float*)d_out);
}